// Round 1
// baseline (640.686 us; speedup 1.0000x reference)
//
#include <hip/hip_runtime.h>

#define NN 100000
#define NE 1600000
// D_IN = D_H = 64, D_OUT = 16

// ---------------- CSR build ----------------

__global__ void zero_kernel(int* __restrict__ p, int n) {
    int i = blockIdx.x * blockDim.x + threadIdx.x;
    if (i < n) p[i] = 0;
}

__global__ void hist_kernel(const int* __restrict__ dst, int* __restrict__ cnt, int e) {
    int i = blockIdx.x * blockDim.x + threadIdx.x;
    if (i < e) atomicAdd(&cnt[dst[i]], 1);
}

// chunk = 1024 per block (256 threads x 4)
__global__ void scan_sums_kernel(const int* __restrict__ cnt, int* __restrict__ bsum, int n) {
    __shared__ int red[256];
    int tid = threadIdx.x;
    int base = blockIdx.x * 1024 + tid * 4;
    int s = 0;
#pragma unroll
    for (int i = 0; i < 4; i++) {
        int v = base + i;
        if (v < n) s += cnt[v];
    }
    red[tid] = s;
    __syncthreads();
    for (int off = 128; off > 0; off >>= 1) {
        if (tid < off) red[tid] += red[tid + off];
        __syncthreads();
    }
    if (tid == 0) bsum[blockIdx.x] = red[0];
}

__global__ void scan_off_kernel(const int* __restrict__ bsum, int* __restrict__ boff, int nb) {
    int run = 0;
    for (int b = 0; b < nb; b++) { boff[b] = run; run += bsum[b]; }
}

__global__ void scan_write_kernel(const int* __restrict__ cnt, const int* __restrict__ boff,
                                  int* __restrict__ start, int* __restrict__ cursor,
                                  float* __restrict__ dinv, int n) {
    __shared__ int tsum[256];
    int tid = threadIdx.x;
    int base = blockIdx.x * 1024 + tid * 4;
    int c[4];
    int s = 0;
#pragma unroll
    for (int i = 0; i < 4; i++) {
        int v = base + i;
        c[i] = (v < n) ? cnt[v] : 0;
        s += c[i];
    }
    tsum[tid] = s;
    __syncthreads();
    // Hillis-Steele inclusive scan over 256 thread sums
    for (int off = 1; off < 256; off <<= 1) {
        int v = 0;
        if (tid >= off) v = tsum[tid - off];
        __syncthreads();
        if (tid >= off) tsum[tid] += v;
        __syncthreads();
    }
    int pre = boff[blockIdx.x] + tsum[tid] - s;  // exclusive prefix for this thread
#pragma unroll
    for (int i = 0; i < 4; i++) {
        int v = base + i;
        if (v < n) {
            start[v]  = pre;
            cursor[v] = pre;
            dinv[v]   = rsqrtf((float)c[i] + 1.0f);  // +1 self-loop
            pre += c[i];
        }
    }
}

__global__ void fill_kernel(const int* __restrict__ src, const int* __restrict__ dst,
                            int* __restrict__ cursor, int* __restrict__ csr, int e) {
    int i = blockIdx.x * blockDim.x + threadIdx.x;
    if (i < e) {
        int p = atomicAdd(&cursor[dst[i]], 1);
        csr[p] = src[i];
    }
}

// ---------------- GEMM: s = dinv .* (x @ W) ----------------
// 128 threads, 128 rows/block. G = DOUT/16 column groups, R = G rows/thread.
template <int DOUT>
__global__ __launch_bounds__(128) void gemm_kernel(const float* __restrict__ x,
                                                   const float* __restrict__ W,
                                                   const float* __restrict__ dinv,
                                                   float* __restrict__ s, int n) {
    constexpr int G = DOUT / 16;
    constexpr int R = G;  // rows per thread
    constexpr int ROWS = 128;
    __shared__ float xs[ROWS][65];   // odd stride: 2-way bank alias max (free)
    __shared__ float ws[64][DOUT];
    int tid = threadIdx.x;
    int row0 = blockIdx.x * ROWS;
    for (int i = tid; i < 64 * DOUT; i += 128) ws[i / DOUT][i % DOUT] = W[i];
    for (int i = tid; i < ROWS * 16; i += 128) {
        int r = i >> 4, c = (i & 15) * 4;
        float4 v = make_float4(0.f, 0.f, 0.f, 0.f);
        if (row0 + r < n) v = *(const float4*)&x[(row0 + r) * 64 + c];
        xs[r][c] = v.x; xs[r][c + 1] = v.y; xs[r][c + 2] = v.z; xs[r][c + 3] = v.w;
    }
    __syncthreads();
    int cg = tid % G;
    int rbase = (tid / G) * R;
    float acc[R][16];
#pragma unroll
    for (int i = 0; i < R; i++)
#pragma unroll
        for (int j = 0; j < 16; j++) acc[i][j] = 0.f;
    for (int k = 0; k < 64; k++) {
        float xv[R];
#pragma unroll
        for (int i = 0; i < R; i++) xv[i] = xs[rbase + i][k];
#pragma unroll
        for (int j = 0; j < 4; j++) {
            float4 wv = *(const float4*)&ws[k][cg * 16 + j * 4];
#pragma unroll
            for (int i = 0; i < R; i++) {
                acc[i][j * 4 + 0] += xv[i] * wv.x;
                acc[i][j * 4 + 1] += xv[i] * wv.y;
                acc[i][j * 4 + 2] += xv[i] * wv.z;
                acc[i][j * 4 + 3] += xv[i] * wv.w;
            }
        }
    }
#pragma unroll
    for (int i = 0; i < R; i++) {
        int r = row0 + rbase + i;
        if (r < n) {
            float dv = dinv[r];
#pragma unroll
            for (int j = 0; j < 4; j++) {
                float4 o;
                o.x = acc[i][j * 4 + 0] * dv;
                o.y = acc[i][j * 4 + 1] * dv;
                o.z = acc[i][j * 4 + 2] * dv;
                o.w = acc[i][j * 4 + 3] * dv;
                *(float4*)&s[r * DOUT + cg * 16 + j * 4] = o;
            }
        }
    }
}

// ---------------- Aggregate: out[v] = act(dinv[v]*(s[v] + sum_{u->v} s[u]) + b) ----------------
// One node per D lanes; D=64 -> 1 node/wave, D=16 -> 4 nodes/wave.
template <int D, bool RELU>
__global__ __launch_bounds__(256) void agg_kernel(const float* __restrict__ s,
                                                  const int* __restrict__ csr,
                                                  const int* __restrict__ start,
                                                  const int* __restrict__ cnt,
                                                  const float* __restrict__ dinv,
                                                  const float* __restrict__ bias,
                                                  float* __restrict__ out, int n) {
    constexpr int NPW = 64 / D;
    int tid = threadIdx.x;
    int lane = tid & 63;
    int wave = tid >> 6;
    int col = lane % D;
    int grp = lane / D;
    int node = (blockIdx.x * (256 / 64) + wave) * NPW + grp;
    if (node >= n) return;
    int st = start[node];
    int cn = cnt[node];
    float acc = s[node * D + col];  // self loop
    int e = 0;
    for (; e + 3 < cn; e += 4) {
        int u0 = csr[st + e + 0];
        int u1 = csr[st + e + 1];
        int u2 = csr[st + e + 2];
        int u3 = csr[st + e + 3];
        float a0 = s[u0 * D + col];
        float a1 = s[u1 * D + col];
        float a2 = s[u2 * D + col];
        float a3 = s[u3 * D + col];
        acc += (a0 + a1) + (a2 + a3);
    }
    for (; e < cn; e++) {
        int u = csr[st + e];
        acc += s[u * D + col];
    }
    float o = dinv[node] * acc + bias[col];
    if (RELU) o = fmaxf(o, 0.f);
    out[node * D + col] = o;
}

// ---------------- launch ----------------

extern "C" void kernel_launch(void* const* d_in, const int* in_sizes, int n_in,
                              void* d_out, int out_size, void* d_ws, size_t ws_size,
                              hipStream_t stream) {
    const float* x  = (const float*)d_in[0];
    const int* ei   = (const int*)d_in[1];
    const float* W1 = (const float*)d_in[2];
    const float* b1 = (const float*)d_in[3];
    const float* W2 = (const float*)d_in[4];
    const float* b2 = (const float*)d_in[5];
    const float* W3 = (const float*)d_in[6];
    const float* b3 = (const float*)d_in[7];
    const float* W4 = (const float*)d_in[8];
    const float* b4 = (const float*)d_in[9];
    const int* src = ei;
    const int* dst = ei + NE;

    char* w = (char*)d_ws;
    float* dinv = (float*)w;          w += (size_t)NN * 4;
    int* cnt    = (int*)w;            w += (size_t)NN * 4;
    int* start  = (int*)w;            w += (size_t)NN * 4;
    int* cursor = (int*)w;            w += (size_t)NN * 4;
    int* bsum   = (int*)w;            w += 128 * 4;
    int* boff   = (int*)w;            w += 128 * 4;
    int* csr    = (int*)w;            w += (size_t)NE * 4;
    float* bufA = (float*)w;          w += (size_t)NN * 64 * 4;
    float* bufB = (float*)w;          w += (size_t)NN * 64 * 4;

    const int NB = (NN + 1023) / 1024;  // 98

    zero_kernel<<<(NN + 255) / 256, 256, 0, stream>>>(cnt, NN);
    hist_kernel<<<(NE + 255) / 256, 256, 0, stream>>>(dst, cnt, NE);
    scan_sums_kernel<<<NB, 256, 0, stream>>>(cnt, bsum, NN);
    scan_off_kernel<<<1, 1, 0, stream>>>(bsum, boff, NB);
    scan_write_kernel<<<NB, 256, 0, stream>>>(cnt, boff, start, cursor, dinv, NN);
    fill_kernel<<<(NE + 255) / 256, 256, 0, stream>>>(src, dst, cursor, csr, NE);

    const int GB = (NN + 127) / 128;   // gemm blocks
    const int AB64 = (NN + 3) / 4;     // agg D=64 blocks (4 nodes/block)
    const int AB16 = (NN + 15) / 16;   // agg D=16 blocks (16 nodes/block)

    // Layer 1: x -> bufA (s), agg -> bufB
    gemm_kernel<64><<<GB, 128, 0, stream>>>(x, W1, dinv, bufA, NN);
    agg_kernel<64, true><<<AB64, 256, 0, stream>>>(bufA, csr, start, cnt, dinv, b1, bufB, NN);
    // Layer 2
    gemm_kernel<64><<<GB, 128, 0, stream>>>(bufB, W2, dinv, bufA, NN);
    agg_kernel<64, true><<<AB64, 256, 0, stream>>>(bufA, csr, start, cnt, dinv, b2, bufB, NN);
    // Layer 3
    gemm_kernel<64><<<GB, 128, 0, stream>>>(bufB, W3, dinv, bufA, NN);
    agg_kernel<64, true><<<AB64, 256, 0, stream>>>(bufA, csr, start, cnt, dinv, b3, bufB, NN);
    // Layer 4 (D_OUT=16, no relu) -> d_out
    gemm_kernel<16><<<GB, 128, 0, stream>>>(bufB, W4, dinv, bufA, NN);
    agg_kernel<16, false><<<AB16, 256, 0, stream>>>(bufA, csr, start, cnt, dinv, b4, (float*)d_out, NN);
}

// Round 2
// 557.454 us; speedup vs baseline: 1.1493x; 1.1493x over previous
//
#include <hip/hip_runtime.h>

#define NN 100000
#define NE 1600000
#define BK 512          // nodes per bucket
#define BKSH 9          // log2(BK)
#define NBKT 196        // ceil(NN/BK)

// ---------------- Bucketed CSR build ----------------
// bucket(v) = v >> 9. Edges counting-sorted into bucket order (bedges),
// then per-bucket CSR built in LDS so csr writes stay in a ~32KB window.

__global__ __launch_bounds__(256) void zero_small_kernel(int* __restrict__ p, int n) {
    int i = threadIdx.x + blockIdx.x * 256;
    if (i < n) p[i] = 0;
}

__global__ __launch_bounds__(256) void bhist_kernel(const int* __restrict__ dst,
                                                    int* __restrict__ bcnt, int e) {
    __shared__ int h[NBKT];
    for (int i = threadIdx.x; i < NBKT; i += 256) h[i] = 0;
    __syncthreads();
    for (int i = blockIdx.x * 256 + threadIdx.x; i < e; i += gridDim.x * 256)
        atomicAdd(&h[dst[i] >> BKSH], 1);
    __syncthreads();
    for (int i = threadIdx.x; i < NBKT; i += 256)
        if (h[i]) atomicAdd(&bcnt[i], h[i]);
}

__global__ void bscan_kernel(const int* __restrict__ bcnt, int* __restrict__ bbase,
                             int* __restrict__ bcur) {
    if (threadIdx.x == 0) {
        int run = 0;
        for (int q = 0; q < NBKT; q++) { bbase[q] = run; bcur[q] = run; run += bcnt[q]; }
        bbase[NBKT] = run;
    }
}

// Counting-sort edges into bucket order. Tile = 2048 edges, LDS-staged reorder.
__global__ __launch_bounds__(256) void bscatter_kernel(const int* __restrict__ src,
                                                       const int* __restrict__ dst,
                                                       int* __restrict__ bcur,
                                                       int2* __restrict__ bedges, int e) {
    __shared__ int h[256];
    __shared__ int sc[256];
    __shared__ int gb[NBKT];
    __shared__ int2 stage[2048];
    int tid = threadIdx.x;
    for (int tile = blockIdx.x * 2048; tile < e; tile += gridDim.x * 2048) {
        int cnt_tile = min(2048, e - tile);
        h[tid] = 0;
        __syncthreads();
        int2 pr[8]; int rk[8]; int bk[8];
#pragma unroll
        for (int j = 0; j < 8; j++) {
            int li = tid + j * 256;
            if (li < cnt_tile) {
                pr[j].x = src[tile + li];
                pr[j].y = dst[tile + li];
                bk[j] = pr[j].y >> BKSH;
                rk[j] = atomicAdd(&h[bk[j]], 1);
            } else bk[j] = -1;
        }
        __syncthreads();
        int v = h[tid];          // final per-bucket count for this tile
        sc[tid] = v;
        __syncthreads();
        for (int off = 1; off < 256; off <<= 1) {
            int t2 = (tid >= off) ? sc[tid - off] : 0;
            __syncthreads();
            sc[tid] += t2;
            __syncthreads();
        }
        int excl = sc[tid] - v;
        if (tid < NBKT && v > 0) gb[tid] = atomicAdd(&bcur[tid], v);
        __syncthreads();
        sc[tid] = excl;          // sc now = exclusive scan, lookup by bucket id
        __syncthreads();
#pragma unroll
        for (int j = 0; j < 8; j++)
            if (bk[j] >= 0) stage[sc[bk[j]] + rk[j]] = pr[j];
        __syncthreads();
#pragma unroll
        for (int j = 0; j < 8; j++) {
            int li = tid + j * 256;
            if (li < cnt_tile) {
                int2 p2 = stage[li];
                int b = p2.y >> BKSH;
                bedges[gb[b] + (li - sc[b])] = p2;
            }
        }
        __syncthreads();
    }
}

// One block per bucket: LDS degree hist + scan + cursor placement.
// Emits start/cnt/dinv for the bucket's nodes and the csr slice.
__global__ __launch_bounds__(256) void bfill_kernel(const int2* __restrict__ bedges,
                                                    const int* __restrict__ bbase,
                                                    int* __restrict__ start,
                                                    int* __restrict__ cnt,
                                                    float* __restrict__ dinv,
                                                    int* __restrict__ csr) {
    __shared__ int lcnt[BK];
    __shared__ int lsum[256];
    __shared__ int lstart[BK];
    __shared__ int lcur[BK];
    int q = blockIdx.x, tid = threadIdx.x;
    int ebase = bbase[q], ec = bbase[q + 1] - ebase;
    int nbase = q * BK;
    lcnt[tid] = 0; lcnt[tid + 256] = 0;
    __syncthreads();
    for (int i = tid; i < ec; i += 256)
        atomicAdd(&lcnt[bedges[ebase + i].y - nbase], 1);
    __syncthreads();
    int a = lcnt[2 * tid], b = lcnt[2 * tid + 1];
    int s = a + b;
    lsum[tid] = s;
    __syncthreads();
    for (int off = 1; off < 256; off <<= 1) {
        int t2 = (tid >= off) ? lsum[tid - off] : 0;
        __syncthreads();
        lsum[tid] += t2;
        __syncthreads();
    }
    int ex = lsum[tid] - s;
    lstart[2 * tid] = ex;       lstart[2 * tid + 1] = ex + a;
    lcur[2 * tid] = ex;         lcur[2 * tid + 1] = ex + a;
    __syncthreads();
    for (int l = tid; l < BK; l += 256) {
        int v = nbase + l;
        if (v < NN) {
            start[v] = ebase + lstart[l];
            cnt[v]   = lcnt[l];
            dinv[v]  = rsqrtf((float)lcnt[l] + 1.0f);
        }
    }
    for (int i = tid; i < ec; i += 256) {
        int2 p2 = bedges[ebase + i];
        int r = atomicAdd(&lcur[p2.y - nbase], 1);
        csr[ebase + r] = p2.x;
    }
}

// ---------------- GEMM: s = dinv .* (x @ W) ----------------
template <int DOUT>
__global__ __launch_bounds__(128) void gemm_kernel(const float* __restrict__ x,
                                                   const float* __restrict__ W,
                                                   const float* __restrict__ dinv,
                                                   float* __restrict__ s, int n) {
    constexpr int G = DOUT / 16;
    constexpr int R = G;
    constexpr int ROWS = 128;
    __shared__ float xs[ROWS][65];
    __shared__ float ws[64][DOUT];
    int tid = threadIdx.x;
    int row0 = blockIdx.x * ROWS;
    for (int i = tid; i < 64 * DOUT; i += 128) ws[i / DOUT][i % DOUT] = W[i];
    for (int i = tid; i < ROWS * 16; i += 128) {
        int r = i >> 4, c = (i & 15) * 4;
        float4 v = make_float4(0.f, 0.f, 0.f, 0.f);
        if (row0 + r < n) v = *(const float4*)&x[(row0 + r) * 64 + c];
        xs[r][c] = v.x; xs[r][c + 1] = v.y; xs[r][c + 2] = v.z; xs[r][c + 3] = v.w;
    }
    __syncthreads();
    int cg = tid % G;
    int rbase = (tid / G) * R;
    float acc[R][16];
#pragma unroll
    for (int i = 0; i < R; i++)
#pragma unroll
        for (int j = 0; j < 16; j++) acc[i][j] = 0.f;
    for (int k = 0; k < 64; k++) {
        float xv[R];
#pragma unroll
        for (int i = 0; i < R; i++) xv[i] = xs[rbase + i][k];
#pragma unroll
        for (int j = 0; j < 4; j++) {
            float4 wv = *(const float4*)&ws[k][cg * 16 + j * 4];
#pragma unroll
            for (int i = 0; i < R; i++) {
                acc[i][j * 4 + 0] += xv[i] * wv.x;
                acc[i][j * 4 + 1] += xv[i] * wv.y;
                acc[i][j * 4 + 2] += xv[i] * wv.z;
                acc[i][j * 4 + 3] += xv[i] * wv.w;
            }
        }
    }
#pragma unroll
    for (int i = 0; i < R; i++) {
        int r = row0 + rbase + i;
        if (r < n) {
            float dv = dinv[r];
#pragma unroll
            for (int j = 0; j < 4; j++) {
                float4 o;
                o.x = acc[i][j * 4 + 0] * dv;
                o.y = acc[i][j * 4 + 1] * dv;
                o.z = acc[i][j * 4 + 2] * dv;
                o.w = acc[i][j * 4 + 3] * dv;
                *(float4*)&s[r * DOUT + cg * 16 + j * 4] = o;
            }
        }
    }
}

// ---------------- Aggregate ----------------
template <int D, bool RELU>
__global__ __launch_bounds__(256) void agg_kernel(const float* __restrict__ s,
                                                  const int* __restrict__ csr,
                                                  const int* __restrict__ start,
                                                  const int* __restrict__ cnt,
                                                  const float* __restrict__ dinv,
                                                  const float* __restrict__ bias,
                                                  float* __restrict__ out, int n) {
    constexpr int NPW = 64 / D;
    int tid = threadIdx.x;
    int lane = tid & 63;
    int wave = tid >> 6;
    int col = lane % D;
    int grp = lane / D;
    int node = (blockIdx.x * (256 / 64) + wave) * NPW + grp;
    if (node >= n) return;
    int st = start[node];
    int cn = cnt[node];
    float acc = s[node * D + col];
    int e = 0;
    for (; e + 3 < cn; e += 4) {
        int u0 = csr[st + e + 0];
        int u1 = csr[st + e + 1];
        int u2 = csr[st + e + 2];
        int u3 = csr[st + e + 3];
        float a0 = s[u0 * D + col];
        float a1 = s[u1 * D + col];
        float a2 = s[u2 * D + col];
        float a3 = s[u3 * D + col];
        acc += (a0 + a1) + (a2 + a3);
    }
    for (; e < cn; e++) {
        int u = csr[st + e];
        acc += s[u * D + col];
    }
    float o = dinv[node] * acc + bias[col];
    if (RELU) o = fmaxf(o, 0.f);
    out[node * D + col] = o;
}

// ---------------- launch ----------------

extern "C" void kernel_launch(void* const* d_in, const int* in_sizes, int n_in,
                              void* d_out, int out_size, void* d_ws, size_t ws_size,
                              hipStream_t stream) {
    const float* x  = (const float*)d_in[0];
    const int* ei   = (const int*)d_in[1];
    const float* W1 = (const float*)d_in[2];
    const float* b1 = (const float*)d_in[3];
    const float* W2 = (const float*)d_in[4];
    const float* b2 = (const float*)d_in[5];
    const float* W3 = (const float*)d_in[6];
    const float* b3 = (const float*)d_in[7];
    const float* W4 = (const float*)d_in[8];
    const float* b4 = (const float*)d_in[9];
    const int* src = ei;
    const int* dst = ei + NE;

    char* w = (char*)d_ws;
    float* dinv = (float*)w;          w += (size_t)NN * 4;
    int* cnt    = (int*)w;            w += (size_t)NN * 4;
    int* start  = (int*)w;            w += (size_t)NN * 4;
    int* bcnt   = (int*)w;            w += (size_t)(NBKT + 4) * 4;
    int* bbase  = (int*)w;            w += (size_t)(NBKT + 4) * 4;
    int* bcur   = (int*)w;            w += (size_t)(NBKT + 4) * 4;
    int* csr    = (int*)w;            w += (size_t)NE * 4;
    float* bufA = (float*)w;          w += (size_t)NN * 64 * 4;
    float* bufB = (float*)w;          w += (size_t)NN * 64 * 4;
    // bedges aliases bufA: dead before gemm1 writes bufA
    int2* bedges = (int2*)bufA;       // NE * 8B = 12.8MB < 25.6MB

    zero_small_kernel<<<1, 256, 0, stream>>>(bcnt, NBKT);
    bhist_kernel<<<512, 256, 0, stream>>>(dst, bcnt, NE);
    bscan_kernel<<<1, 64, 0, stream>>>(bcnt, bbase, bcur);
    bscatter_kernel<<<512, 256, 0, stream>>>(src, dst, bcur, bedges, NE);
    bfill_kernel<<<NBKT, 256, 0, stream>>>(bedges, bbase, start, cnt, dinv, csr);

    const int GB = (NN + 127) / 128;
    const int AB64 = (NN + 3) / 4;
    const int AB16 = (NN + 15) / 16;

    gemm_kernel<64><<<GB, 128, 0, stream>>>(x, W1, dinv, bufA, NN);
    agg_kernel<64, true><<<AB64, 256, 0, stream>>>(bufA, csr, start, cnt, dinv, b1, bufB, NN);
    gemm_kernel<64><<<GB, 128, 0, stream>>>(bufB, W2, dinv, bufA, NN);
    agg_kernel<64, true><<<AB64, 256, 0, stream>>>(bufA, csr, start, cnt, dinv, b2, bufB, NN);
    gemm_kernel<64><<<GB, 128, 0, stream>>>(bufB, W3, dinv, bufA, NN);
    agg_kernel<64, true><<<AB64, 256, 0, stream>>>(bufA, csr, start, cnt, dinv, b3, bufB, NN);
    gemm_kernel<16><<<GB, 128, 0, stream>>>(bufB, W4, dinv, bufA, NN);
    agg_kernel<16, false><<<AB16, 256, 0, stream>>>(bufA, csr, start, cnt, dinv, b4, (float*)d_out, NN);
}

// Round 3
// 449.766 us; speedup vs baseline: 1.4245x; 1.2394x over previous
//
#include <hip/hip_runtime.h>
#include <hip/hip_fp16.h>

#define NN 100000
#define NE 1600000
#define BK 512          // nodes per bucket
#define BKSH 9          // log2(BK)
#define NBKT 196        // ceil(NN/BK)

// ---------------- Bucketed CSR build ----------------

__global__ __launch_bounds__(256) void zero_small_kernel(int* __restrict__ p, int n) {
    int i = threadIdx.x + blockIdx.x * 256;
    if (i < n) p[i] = 0;
}

__global__ __launch_bounds__(256) void bhist_kernel(const int* __restrict__ dst,
                                                    int* __restrict__ bcnt, int e) {
    __shared__ int h[NBKT];
    for (int i = threadIdx.x; i < NBKT; i += 256) h[i] = 0;
    __syncthreads();
    for (int i = blockIdx.x * 256 + threadIdx.x; i < e; i += gridDim.x * 256)
        atomicAdd(&h[dst[i] >> BKSH], 1);
    __syncthreads();
    for (int i = threadIdx.x; i < NBKT; i += 256)
        if (h[i]) atomicAdd(&bcnt[i], h[i]);
}

// parallel scan over NBKT bucket counts (was a 1-thread serial loop: ~196
// dependent global round-trips ~= tens of us)
__global__ __launch_bounds__(256) void bscan_kernel(const int* __restrict__ bcnt,
                                                    int* __restrict__ bbase,
                                                    int* __restrict__ bcur) {
    __shared__ int sc[256];
    int tid = threadIdx.x;
    int v = (tid < NBKT) ? bcnt[tid] : 0;
    sc[tid] = v;
    __syncthreads();
    for (int off = 1; off < 256; off <<= 1) {
        int t2 = (tid >= off) ? sc[tid - off] : 0;
        __syncthreads();
        sc[tid] += t2;
        __syncthreads();
    }
    if (tid < NBKT) {
        int ex = sc[tid] - v;
        bbase[tid] = ex;
        bcur[tid] = ex;
    }
    if (tid == 255) bbase[NBKT] = sc[255];
}

// Counting-sort edges into bucket order. Tile = 2048 edges, LDS-staged reorder.
__global__ __launch_bounds__(256) void bscatter_kernel(const int* __restrict__ src,
                                                       const int* __restrict__ dst,
                                                       int* __restrict__ bcur,
                                                       int2* __restrict__ bedges, int e) {
    __shared__ int h[256];
    __shared__ int sc[256];
    __shared__ int gb[NBKT];
    __shared__ int2 stage[2048];
    int tid = threadIdx.x;
    for (int tile = blockIdx.x * 2048; tile < e; tile += gridDim.x * 2048) {
        int cnt_tile = min(2048, e - tile);
        h[tid] = 0;
        __syncthreads();
        int2 pr[8]; int rk[8]; int bk[8];
#pragma unroll
        for (int j = 0; j < 8; j++) {
            int li = tid + j * 256;
            if (li < cnt_tile) {
                pr[j].x = src[tile + li];
                pr[j].y = dst[tile + li];
                bk[j] = pr[j].y >> BKSH;
                rk[j] = atomicAdd(&h[bk[j]], 1);
            } else bk[j] = -1;
        }
        __syncthreads();
        int v = h[tid];
        sc[tid] = v;
        __syncthreads();
        for (int off = 1; off < 256; off <<= 1) {
            int t2 = (tid >= off) ? sc[tid - off] : 0;
            __syncthreads();
            sc[tid] += t2;
            __syncthreads();
        }
        int excl = sc[tid] - v;
        if (tid < NBKT && v > 0) gb[tid] = atomicAdd(&bcur[tid], v);
        __syncthreads();
        sc[tid] = excl;
        __syncthreads();
#pragma unroll
        for (int j = 0; j < 8; j++)
            if (bk[j] >= 0) stage[sc[bk[j]] + rk[j]] = pr[j];
        __syncthreads();
#pragma unroll
        for (int j = 0; j < 8; j++) {
            int li = tid + j * 256;
            if (li < cnt_tile) {
                int2 p2 = stage[li];
                int b = p2.y >> BKSH;
                bedges[gb[b] + (li - sc[b])] = p2;
            }
        }
        __syncthreads();
    }
}

// One block per bucket: LDS degree hist + scan + cursor placement.
__global__ __launch_bounds__(256) void bfill_kernel(const int2* __restrict__ bedges,
                                                    const int* __restrict__ bbase,
                                                    int* __restrict__ start,
                                                    int* __restrict__ cnt,
                                                    float* __restrict__ dinv,
                                                    int* __restrict__ csr) {
    __shared__ int lcnt[BK];
    __shared__ int lsum[256];
    __shared__ int lstart[BK];
    __shared__ int lcur[BK];
    int q = blockIdx.x, tid = threadIdx.x;
    int ebase = bbase[q], ec = bbase[q + 1] - ebase;
    int nbase = q * BK;
    lcnt[tid] = 0; lcnt[tid + 256] = 0;
    __syncthreads();
    for (int i = tid; i < ec; i += 256)
        atomicAdd(&lcnt[bedges[ebase + i].y - nbase], 1);
    __syncthreads();
    int a = lcnt[2 * tid], b = lcnt[2 * tid + 1];
    int s = a + b;
    lsum[tid] = s;
    __syncthreads();
    for (int off = 1; off < 256; off <<= 1) {
        int t2 = (tid >= off) ? lsum[tid - off] : 0;
        __syncthreads();
        lsum[tid] += t2;
        __syncthreads();
    }
    int ex = lsum[tid] - s;
    lstart[2 * tid] = ex;       lstart[2 * tid + 1] = ex + a;
    lcur[2 * tid] = ex;         lcur[2 * tid + 1] = ex + a;
    __syncthreads();
    for (int l = tid; l < BK; l += 256) {
        int v = nbase + l;
        if (v < NN) {
            start[v] = ebase + lstart[l];
            cnt[v]   = lcnt[l];
            dinv[v]  = rsqrtf((float)lcnt[l] + 1.0f);
        }
    }
    for (int i = tid; i < ec; i += 256) {
        int2 p2 = bedges[ebase + i];
        int r = atomicAdd(&lcur[p2.y - nbase], 1);
        csr[ebase + r] = p2.x;
    }
}

// ---------------- GEMM: s = half( dinv .* (x @ W) ) ----------------
template <int DOUT>
__global__ __launch_bounds__(128) void gemm_kernel(const float* __restrict__ x,
                                                   const float* __restrict__ W,
                                                   const float* __restrict__ dinv,
                                                   __half* __restrict__ s, int n) {
    constexpr int G = DOUT / 16;
    constexpr int R = G;
    constexpr int ROWS = 128;
    __shared__ float xs[ROWS][65];
    __shared__ float ws[64][DOUT];
    int tid = threadIdx.x;
    int row0 = blockIdx.x * ROWS;
    for (int i = tid; i < 64 * DOUT; i += 128) ws[i / DOUT][i % DOUT] = W[i];
    for (int i = tid; i < ROWS * 16; i += 128) {
        int r = i >> 4, c = (i & 15) * 4;
        float4 v = make_float4(0.f, 0.f, 0.f, 0.f);
        if (row0 + r < n) v = *(const float4*)&x[(row0 + r) * 64 + c];
        xs[r][c] = v.x; xs[r][c + 1] = v.y; xs[r][c + 2] = v.z; xs[r][c + 3] = v.w;
    }
    __syncthreads();
    int cg = tid % G;
    int rbase = (tid / G) * R;
    float acc[R][16];
#pragma unroll
    for (int i = 0; i < R; i++)
#pragma unroll
        for (int j = 0; j < 16; j++) acc[i][j] = 0.f;
    for (int k = 0; k < 64; k++) {
        float xv[R];
#pragma unroll
        for (int i = 0; i < R; i++) xv[i] = xs[rbase + i][k];
#pragma unroll
        for (int j = 0; j < 4; j++) {
            float4 wv = *(const float4*)&ws[k][cg * 16 + j * 4];
#pragma unroll
            for (int i = 0; i < R; i++) {
                acc[i][j * 4 + 0] += xv[i] * wv.x;
                acc[i][j * 4 + 1] += xv[i] * wv.y;
                acc[i][j * 4 + 2] += xv[i] * wv.z;
                acc[i][j * 4 + 3] += xv[i] * wv.w;
            }
        }
    }
#pragma unroll
    for (int i = 0; i < R; i++) {
        int r = row0 + rbase + i;
        if (r < n) {
            float dv = dinv[r];
            union { ushort u[16]; uint4 q[2]; } pk;
#pragma unroll
            for (int j = 0; j < 16; j++)
                pk.u[j] = __half_as_ushort(__float2half_rn(acc[i][j] * dv));
            uint4* sp = (uint4*)&s[(size_t)r * DOUT + cg * 16];
            sp[0] = pk.q[0];
            sp[1] = pk.q[1];
        }
    }
}

// ---------------- Aggregate: out[v] = act(dinv[v]*(s[v] + sum_{u->v} s[u]) + b) ----------------
template <int D, bool RELU>
__global__ __launch_bounds__(256) void agg_kernel(const __half* __restrict__ s,
                                                  const int* __restrict__ csr,
                                                  const int* __restrict__ start,
                                                  const int* __restrict__ cnt,
                                                  const float* __restrict__ dinv,
                                                  const float* __restrict__ bias,
                                                  float* __restrict__ out, int n) {
    constexpr int NPW = 64 / D;
    int tid = threadIdx.x;
    int lane = tid & 63;
    int wave = tid >> 6;
    int col = lane % D;
    int grp = lane / D;
    int node = (blockIdx.x * (256 / 64) + wave) * NPW + grp;
    if (node >= n) return;
    int st = start[node];
    int cn = cnt[node];
    float acc = __half2float(s[(size_t)node * D + col]);  // self loop
    int e = 0;
    for (; e + 7 < cn; e += 8) {
        int u[8]; float a[8];
#pragma unroll
        for (int j = 0; j < 8; j++) u[j] = csr[st + e + j];
#pragma unroll
        for (int j = 0; j < 8; j++) a[j] = __half2float(s[(size_t)u[j] * D + col]);
        acc += ((a[0] + a[1]) + (a[2] + a[3])) + ((a[4] + a[5]) + (a[6] + a[7]));
    }
    for (; e + 3 < cn; e += 4) {
        int u0 = csr[st + e + 0];
        int u1 = csr[st + e + 1];
        int u2 = csr[st + e + 2];
        int u3 = csr[st + e + 3];
        float a0 = __half2float(s[(size_t)u0 * D + col]);
        float a1 = __half2float(s[(size_t)u1 * D + col]);
        float a2 = __half2float(s[(size_t)u2 * D + col]);
        float a3 = __half2float(s[(size_t)u3 * D + col]);
        acc += (a0 + a1) + (a2 + a3);
    }
    for (; e < cn; e++) {
        int u = csr[st + e];
        acc += __half2float(s[(size_t)u * D + col]);
    }
    float o = dinv[node] * acc + bias[col];
    if (RELU) o = fmaxf(o, 0.f);
    out[node * D + col] = o;
}

// ---------------- launch ----------------

extern "C" void kernel_launch(void* const* d_in, const int* in_sizes, int n_in,
                              void* d_out, int out_size, void* d_ws, size_t ws_size,
                              hipStream_t stream) {
    const float* x  = (const float*)d_in[0];
    const int* ei   = (const int*)d_in[1];
    const float* W1 = (const float*)d_in[2];
    const float* b1 = (const float*)d_in[3];
    const float* W2 = (const float*)d_in[4];
    const float* b2 = (const float*)d_in[5];
    const float* W3 = (const float*)d_in[6];
    const float* b3 = (const float*)d_in[7];
    const float* W4 = (const float*)d_in[8];
    const float* b4 = (const float*)d_in[9];
    const int* src = ei;
    const int* dst = ei + NE;

    char* w = (char*)d_ws;
    float* dinv  = (float*)w;         w += (size_t)NN * 4;
    int* cnt     = (int*)w;           w += (size_t)NN * 4;
    int* start   = (int*)w;           w += (size_t)NN * 4;
    int* bcnt    = (int*)w;           w += (size_t)(NBKT + 4) * 4;
    int* bbase   = (int*)w;           w += (size_t)(NBKT + 4) * 4;
    int* bcur    = (int*)w;           w += (size_t)(NBKT + 4) * 4;
    int* csr     = (int*)w;           w += (size_t)NE * 4;
    __half* sbuf = (__half*)w;        w += (size_t)NN * 64 * 2;
    float* hbuf  = (float*)w;         w += (size_t)NN * 64 * 4;
    int2* bedges = (int2*)w;          w += (size_t)NE * 8;

    zero_small_kernel<<<1, 256, 0, stream>>>(bcnt, NBKT);
    bhist_kernel<<<512, 256, 0, stream>>>(dst, bcnt, NE);
    bscan_kernel<<<1, 256, 0, stream>>>(bcnt, bbase, bcur);
    bscatter_kernel<<<512, 256, 0, stream>>>(src, dst, bcur, bedges, NE);
    bfill_kernel<<<NBKT, 256, 0, stream>>>(bedges, bbase, start, cnt, dinv, csr);

    const int GB = (NN + 127) / 128;
    const int AB64 = (NN + 3) / 4;
    const int AB16 = (NN + 15) / 16;

    // h-space buffers alternate: gemm (fp32 in -> half s), agg (half s -> fp32 h)
    gemm_kernel<64><<<GB, 128, 0, stream>>>(x, W1, dinv, sbuf, NN);
    agg_kernel<64, true><<<AB64, 256, 0, stream>>>(sbuf, csr, start, cnt, dinv, b1, hbuf, NN);
    gemm_kernel<64><<<GB, 128, 0, stream>>>(hbuf, W2, dinv, sbuf, NN);
    agg_kernel<64, true><<<AB64, 256, 0, stream>>>(sbuf, csr, start, cnt, dinv, b2, hbuf, NN);
    gemm_kernel<64><<<GB, 128, 0, stream>>>(hbuf, W3, dinv, sbuf, NN);
    agg_kernel<64, true><<<AB64, 256, 0, stream>>>(sbuf, csr, start, cnt, dinv, b3, hbuf, NN);
    gemm_kernel<16><<<GB, 128, 0, stream>>>(hbuf, W4, dinv, sbuf, NN);
    agg_kernel<16, false><<<AB16, 256, 0, stream>>>(sbuf, csr, start, cnt, dinv, b4, (float*)d_out, NN);
}